// Round 5
// baseline (353.864 us; speedup 1.0000x reference)
//
#include <hip/hip_runtime.h>

// Cosine similarity with 4 diagonal neighbors, summed.
// Input: (2048, 2048, 1, 16) fp32. Output: (2048, 2048) fp32.
//
// R5: deep-MLP staging. R4 (~99 us) was staging-latency bound: the rolled
// staging loop (trip 9/10, load->cvt->ds_write chain) kept ~1 load in
// flight per wave -> effective 3.3 TB/s vs 6.7 achievable. Now chunk count
// is padded to 2560 = 10*256 (p clamped to 611; duplicate same-value LDS
// writes are benign) and staging is split into two fully-unrolled phases:
// 10 independent global_load_dwordx4 back-to-back into registers, then
// cvt+LDS writes. 10 loads/wave x 20 waves = 200 KB in flight per CU >>
// the ~9 KB/CU latency-BW product.
//
// LDS: fp16, 48 B/px (16 data halves + 8 pad): 16B-aligned for
// ds_read_b128; start bank (12p)%32 covers all 32 banks once per 8 px ->
// conflict-free minimum (verified 0 SQ_LDS_BANK_CONFLICT in R1/R2).
// 29376 B/block -> 5 blocks/CU = 20 waves.

#define IMG_H 2048
#define IMG_W 2048
#define IMG_C 16

#define TX 32
#define TY 16
#define HX (TX + 2)      // 34
#define HY (TY + 2)      // 18
#define NPIX (HX * HY)   // 612
#define PSTRIDE 24       // halves per pixel slot (16 data + 8 pad) = 48 B
#define NSTAGE 10        // 2560 chunks = 10 * 256 threads

typedef _Float16 half2_t __attribute__((ext_vector_type(2)));

__device__ __forceinline__ float vdot16(const float4& x0, const float4& x1,
                                        const float4& y0, const float4& y1) {
    const half2_t* xa = (const half2_t*)&x0;
    const half2_t* xb = (const half2_t*)&x1;
    const half2_t* ya = (const half2_t*)&y0;
    const half2_t* yb = (const half2_t*)&y1;
    float acc = 0.0f;
    #pragma unroll
    for (int j = 0; j < 4; ++j) acc = __builtin_amdgcn_fdot2(xa[j], ya[j], acc, false);
    #pragma unroll
    for (int j = 0; j < 4; ++j) acc = __builtin_amdgcn_fdot2(xb[j], yb[j], acc, false);
    return acc;
}

__global__ __launch_bounds__(256, 5) void cos_sim_kernel(
    const float* __restrict__ in, float* __restrict__ out) {
    __shared__ _Float16 tile[NPIX * PSTRIDE];   // 29376 B

    const int tid = threadIdx.y * 32 + threadIdx.x;
    const int bx = blockIdx.x * TX;
    const int by = blockIdx.y * TY;

    // ---- Phase 1a: issue all 10 staging loads (independent, deep MLP) ----
    float4 v[NSTAGE];
    int pp[NSTAGE];
    int kk[NSTAGE];
    #pragma unroll
    for (int j = 0; j < NSTAGE; ++j) {
        const int i = tid + j * 256;
        const int p = min(i >> 2, NPIX - 1);   // tail chunks duplicate px 611
        const int k = i & 3;
        const int r = p / HX;
        const int c = p - r * HX;
        int gy = by + r - 1;
        int gx = bx + c - 1;
        gy = min(max(gy, 0), IMG_H - 1);
        gx = min(max(gx, 0), IMG_W - 1);
        pp[j] = p;
        kk[j] = k;
        v[j] = *(const float4*)(in + ((size_t)gy * IMG_W + gx) * IMG_C + k * 4);
    }
    // ---- Phase 1b: convert + write LDS ----
    #pragma unroll
    for (int j = 0; j < NSTAGE; ++j) {
        half2_t h0 = __builtin_bit_cast(half2_t, __builtin_amdgcn_cvt_pkrtz(v[j].x, v[j].y));
        half2_t h1 = __builtin_bit_cast(half2_t, __builtin_amdgcn_cvt_pkrtz(v[j].z, v[j].w));
        half2_t* dst = (half2_t*)(tile + pp[j] * PSTRIDE + kk[j] * 4);
        dst[0] = h0;
        dst[1] = h1;
    }
    __syncthreads();

    // ---- Phase 2: compute 2 output pixels per thread ----
    #pragma unroll
    for (int rr = 0; rr < 2; ++rr) {
        const int r = threadIdx.y + rr * 8;    // tile row 0..15
        const int c = threadIdx.x;             // tile col 0..31
        const int gy = by + r;
        const int gx = bx + c;
        const int p = (r + 1) * HX + (c + 1);

        const _Float16* t = tile + p * PSTRIDE;
        const float4 a0 = *(const float4*)(t);       // 8 halves
        const float4 a1 = *(const float4*)(t + 8);   // 8 halves
        const float na = vdot16(a0, a1, a0, a1);

        float sim = 0.0f;
        #pragma unroll
        for (int q = 0; q < 4; ++q) {
            const int dy = (q & 2) ? 1 : -1;
            const int dx = (q & 1) ? 1 : -1;
            const int np = p + dy * HX + dx;
            const _Float16* u = tile + np * PSTRIDE;
            const float4 b0 = *(const float4*)(u);
            const float4 b1 = *(const float4*)(u + 8);
            const float dot = vdot16(a0, a1, b0, b1);
            const float nb  = vdot16(b0, b1, b0, b1);
            const bool valid = ((unsigned)(gy + dy) < IMG_H) && ((unsigned)(gx + dx) < IMG_W);
            const float contrib = dot * rsqrtf(fmaxf(na * nb, 1e-16f));
            sim += valid ? contrib : 0.0f;
        }
        out[(size_t)gy * IMG_W + gx] = sim;
    }
}

extern "C" void kernel_launch(void* const* d_in, const int* in_sizes, int n_in,
                              void* d_out, int out_size, void* d_ws, size_t ws_size,
                              hipStream_t stream) {
    const float* in = (const float*)d_in[0];
    float* out = (float*)d_out;
    dim3 block(32, 8, 1);
    dim3 grid(IMG_W / TX, IMG_H / TY, 1);
    cos_sim_kernel<<<grid, block, 0, stream>>>(in, out);
}

// Round 6
// 353.027 us; speedup vs baseline: 1.0024x; 1.0024x over previous
//
#include <hip/hip_runtime.h>

// Cosine similarity with 4 diagonal neighbors, summed.
// Input: (2048, 2048, 1, 16) fp32. Output: (2048, 2048) fp32.
//
// R6: full occupancy + XCD-band swizzle.
// R5 (deep-MLP staging) was NEUTRAL -> staging latency per wave wasn't the
// wall. Remaining suspects: (a) only 20/32 waves per CU (29 KB LDS -> 5
// blocks/CU), (b) round-robin block->XCD dispatch scatters adjacent tiles
// across XCDs, so halo re-reads miss L2 and each XCD's DRAM stream is
// strided. This round: 32x8 tile (halo 34x10 = 16.3 KB LDS) with
// __launch_bounds__(256,8) -> 8 blocks/CU = 32 waves (100% occupancy);
// blockIdx swizzle gives each XCD (blockIdx&7) a contiguous 256-row image
// band traversed row-major -> halo reuse hits that XCD's L2, HBM reads
// become 8 long sequential streams.
//
// LDS layout unchanged: fp16, 48 B/px (16 halves + 8 pad), 16B-aligned for
// ds_read_b128; start bank (12p)%32 -> balanced, 0 conflicts measured.

#define IMG_H 2048
#define IMG_W 2048
#define IMG_C 16

#define TX 32
#define TY 8
#define HX (TX + 2)      // 34
#define HY (TY + 2)      // 10
#define NPIX (HX * HY)   // 340
#define PSTRIDE 24       // halves per pixel slot (16 data + 8 pad) = 48 B
#define NSTAGE 6         // ceil(340*4 / 256) -> 1536 padded chunks

#define TILES_X (IMG_W / TX)          // 64
#define TILES_Y (IMG_H / TY)          // 256
#define BAND_TY (TILES_Y / 8)         // 32 tile-rows per XCD band

typedef _Float16 half2_t __attribute__((ext_vector_type(2)));

__device__ __forceinline__ float vdot16(const float4& x0, const float4& x1,
                                        const float4& y0, const float4& y1) {
    const half2_t* xa = (const half2_t*)&x0;
    const half2_t* xb = (const half2_t*)&x1;
    const half2_t* ya = (const half2_t*)&y0;
    const half2_t* yb = (const half2_t*)&y1;
    float acc = 0.0f;
    #pragma unroll
    for (int j = 0; j < 4; ++j) acc = __builtin_amdgcn_fdot2(xa[j], ya[j], acc, false);
    #pragma unroll
    for (int j = 0; j < 4; ++j) acc = __builtin_amdgcn_fdot2(xb[j], yb[j], acc, false);
    return acc;
}

__global__ __launch_bounds__(256, 8) void cos_sim_kernel(
    const float* __restrict__ in, float* __restrict__ out) {
    __shared__ _Float16 tile[NPIX * PSTRIDE];   // 16320 B

    const int tid = threadIdx.y * 32 + threadIdx.x;

    // XCD-band swizzle: dispatch round-robins blocks over 8 XCDs, so
    // blockIdx&7 selects the XCD. Give each XCD a horizontal band of 32
    // tile-rows, traversed row-major (x fastest) for streaming + L2 reuse.
    const int b = blockIdx.x;
    const int xcd = b & 7;
    const int i2 = b >> 3;                 // 0..2047
    const int tyl = i2 >> 6;               // 0..31 within band
    const int txi = i2 & 63;               // 0..63
    const int bx = txi * TX;
    const int by = (xcd * BAND_TY + tyl) * TY;

    // ---- Stage (HY x HX) halo tile into LDS as fp16 ----
    float4 v[NSTAGE];
    int dof[NSTAGE];
    #pragma unroll
    for (int j = 0; j < NSTAGE; ++j) {
        const int i = tid + j * 256;
        const int p = min(i >> 2, NPIX - 1);   // tail duplicates px 339 (benign)
        const int k = i & 3;
        const int r = p / HX;
        const int c = p - r * HX;
        int gy = by + r - 1;
        int gx = bx + c - 1;
        gy = min(max(gy, 0), IMG_H - 1);
        gx = min(max(gx, 0), IMG_W - 1);
        dof[j] = p * PSTRIDE + k * 4;          // half-element offset
        v[j] = *(const float4*)(in + ((size_t)gy * IMG_W + gx) * IMG_C + k * 4);
    }
    #pragma unroll
    for (int j = 0; j < NSTAGE; ++j) {
        half2_t h0 = __builtin_bit_cast(half2_t, __builtin_amdgcn_cvt_pkrtz(v[j].x, v[j].y));
        half2_t h1 = __builtin_bit_cast(half2_t, __builtin_amdgcn_cvt_pkrtz(v[j].z, v[j].w));
        half2_t* dst = (half2_t*)(tile + dof[j]);
        dst[0] = h0;
        dst[1] = h1;
    }
    __syncthreads();

    // ---- Compute 1 output pixel per thread ----
    const int r = threadIdx.y;             // 0..7
    const int c = threadIdx.x;             // 0..31
    const int gy = by + r;
    const int gx = bx + c;
    const int p = (r + 1) * HX + (c + 1);

    const _Float16* t = tile + p * PSTRIDE;
    const float4 a0 = *(const float4*)(t);       // 8 halves
    const float4 a1 = *(const float4*)(t + 8);   // 8 halves
    const float na = vdot16(a0, a1, a0, a1);

    float sim = 0.0f;
    #pragma unroll
    for (int q = 0; q < 4; ++q) {
        const int dy = (q & 2) ? 1 : -1;
        const int dx = (q & 1) ? 1 : -1;
        const int np = p + dy * HX + dx;
        const _Float16* u = tile + np * PSTRIDE;
        const float4 b0 = *(const float4*)(u);
        const float4 b1 = *(const float4*)(u + 8);
        const float dot = vdot16(a0, a1, b0, b1);
        const float nb  = vdot16(b0, b1, b0, b1);
        const bool valid = ((unsigned)(gy + dy) < IMG_H) && ((unsigned)(gx + dx) < IMG_W);
        const float contrib = dot * rsqrtf(fmaxf(na * nb, 1e-16f));
        sim += valid ? contrib : 0.0f;
    }
    out[(size_t)gy * IMG_W + gx] = sim;
}

extern "C" void kernel_launch(void* const* d_in, const int* in_sizes, int n_in,
                              void* d_out, int out_size, void* d_ws, size_t ws_size,
                              hipStream_t stream) {
    const float* in = (const float*)d_in[0];
    float* out = (float*)d_out;
    dim3 block(32, 8, 1);
    dim3 grid(TILES_X * TILES_Y, 1, 1);
    cos_sim_kernel<<<grid, block, 0, stream>>>(in, out);
}